// Round 9
// baseline (104.858 us; speedup 1.0000x reference)
//
#include <hip/hip_runtime.h>
#include <hip/hip_fp16.h>

// 16-qubit, 2-layer circuit, batch 32.  Circuit = P*R1*P*R0 (P = CNOT-ring permutation).
// f(i) = i ^ (i>>1) ^ (bit0(i)?0xC000:0);  f^{-1} = suffix-xor cascade.
// R9: 512 threads x 8 amps/thread (16 waves/CU), fp16 ws, fp32 LDS.  Pass2 schedule
// FIXED vs R8: all R0 gates complete before any conj gate whose selector touches them
// (conj14 is the only conj allowed early - its mask/sel exclude g12).

#define NT 512

__device__ __forceinline__ int fperm(int x) {
  int y = x ^ (x >> 1);
  y ^= (x & 1) ? 0xC000 : 0;
  return y & 0xFFFF;
}

__device__ __forceinline__ int finv16(int x) {
  int s = x;
  s ^= s >> 1; s ^= s >> 2; s ^= s >> 4; s ^= s >> 8;
  int b15 = ((s ^ (s >> 15)) & 1) << 15;
  return (s & 0x7FFF) | b15;
}

__device__ __forceinline__ int swz(int l) {
  return l ^ (((l >> 4) ^ (l >> 7)) & 15);
}

__device__ __forceinline__ __half2 packa(float2 a) { return __floats2half2_rn(a.x, a.y); }
__device__ __forceinline__ float2 unpacka(__half2 h) { return __half22float2(h); }

__device__ __forceinline__ void compute_gates(const float* __restrict__ th, float* gsh) {
  int tid = threadIdx.x;
  if (tid < 32) {
    int l = tid >> 4, q = tid & 15;
    float tx = th[l * 48 + q], ty = th[l * 48 + 16 + q], tz = th[l * 48 + 32 + q];
    float cx, sx, cy, sy, cz, sz;
    sincosf(0.5f * tx, &sx, &cx);
    sincosf(0.5f * ty, &sy, &cy);
    sincosf(0.5f * tz, &sz, &cz);
    float m00r = cy * cx, m00i =  sy * sx;
    float m01r = -sy * cx, m01i = -cy * sx;
    float m10r =  sy * cx, m10i = -cy * sx;
    float m11r =  cy * cx, m11i = -sy * sx;
    float* G = gsh + tid * 8;
    G[0] = cz * m00r + sz * m00i;  G[1] = cz * m00i - sz * m00r;
    G[2] = cz * m01r + sz * m01i;  G[3] = cz * m01i - sz * m01r;
    G[4] = cz * m10r - sz * m10i;  G[5] = cz * m10i + sz * m10r;
    G[6] = cz * m11r - sz * m11i;  G[7] = cz * m11i + sz * m11r;
  }
}

template <int MK, int SK>
__device__ __forceinline__ void greg(float2 (&a)[8], const float* G, int c) {
  const float4* G4 = (const float4*)G;
  float4 r0 = G4[0], r1 = G4[1];
  bool sw = (c != 0);
  float h00r = sw ? r1.z : r0.x, h00i = sw ? r1.w : r0.y;
  float h01r = sw ? r1.x : r0.z, h01i = sw ? r1.y : r0.w;
  float h10r = sw ? r0.z : r1.x, h10i = sw ? r0.w : r1.y;
  float h11r = sw ? r0.x : r1.z, h11i = sw ? r0.y : r1.w;
  constexpr int PV = MK & (-MK);
#pragma unroll
  for (int k = 0; k < 8; k++) {
    if (k & PV) continue;
    const int k2 = k ^ MK;
    const int p0 = __builtin_popcount(k & SK) & 1;
    const int ka = p0 ? k2 : k;
    const int kb = p0 ? k : k2;
    float2 x = a[ka], y = a[kb];
    a[ka] = make_float2(h00r * x.x - h00i * x.y + h01r * y.x - h01i * y.y,
                        h00r * x.y + h00i * x.x + h01r * y.y + h01i * y.x);
    a[kb] = make_float2(h10r * x.x - h10i * x.y + h11r * y.x - h11i * y.y,
                        h10r * x.y + h10i * x.x + h11r * y.y + h11i * y.x);
  }
}

// ====================== Pass 1: R0 on bits 0..11 ======================
// Window bits 0-11; fixed wb = g12..15.  All gates commute (distinct bits).

__global__ void __launch_bounds__(NT, 4) pass1_k(const float* __restrict__ th,
                                                 const float* __restrict__ xre,
                                                 const float* __restrict__ xim,
                                                 __half2* __restrict__ ws) {
  __shared__ float gsh[256];
  __shared__ float2 samp[4096];
  int t = threadIdx.x, blk = blockIdx.x;
  int batch = (blk & 7) + ((blk >> 7) << 3), wb = (blk >> 3) & 15;
  int base = (batch << 16) + (wb << 12);
  float2 a[8];
  {
    const float4* xr4 = (const float4*)(xre + base + (t << 3));
    const float4* xi4 = (const float4*)(xim + base + (t << 3));
#pragma unroll
    for (int q = 0; q < 2; q++) {
      float4 v = xr4[q], w = xi4[q];
      a[4*q+0] = make_float2(v.x, w.x); a[4*q+1] = make_float2(v.y, w.y);
      a[4*q+2] = make_float2(v.z, w.z); a[4*q+3] = make_float2(v.w, w.w);
    }
  }
  compute_gates(th, gsh);
  __syncthreads();   // gsh ready
  // Round A: tile {l0,l1,l2}: l = (t<<3)|k
  greg<1, 1>(a, gsh + 15 * 8, 0);
  greg<2, 2>(a, gsh + 14 * 8, 0);
  greg<4, 4>(a, gsh + 13 * 8, 0);
#pragma unroll
  for (int k = 0; k < 8; k++) samp[swz((t << 3) | k)] = a[k];
  __syncthreads();
  // Round B: tile {l3,l4,l5}: l = (t&7) | (k<<3) | ((t>>3)<<6)
#pragma unroll
  for (int k = 0; k < 8; k++)
    a[k] = samp[swz((t & 7) | (k << 3) | ((t >> 3) << 6))];
  greg<1, 1>(a, gsh + 12 * 8, 0);
  greg<2, 2>(a, gsh + 11 * 8, 0);
  greg<4, 4>(a, gsh + 10 * 8, 0);
#pragma unroll
  for (int k = 0; k < 8; k++)
    samp[swz((t & 7) | (k << 3) | ((t >> 3) << 6))] = a[k];
  __syncthreads();
  // Round C: tile {l6,l7,l8}: l = (t&63) | (k<<6) | ((t>>6)<<9)
#pragma unroll
  for (int k = 0; k < 8; k++)
    a[k] = samp[swz((t & 63) | (k << 6) | ((t >> 6) << 9))];
  greg<1, 1>(a, gsh + 9 * 8, 0);
  greg<2, 2>(a, gsh + 8 * 8, 0);
  greg<4, 4>(a, gsh + 7 * 8, 0);
#pragma unroll
  for (int k = 0; k < 8; k++)
    samp[swz((t & 63) | (k << 6) | ((t >> 6) << 9))] = a[k];
  __syncthreads();
  // Round D: tile {l9,l10,l11}: l = t | (k<<9); store
#pragma unroll
  for (int k = 0; k < 8; k++) a[k] = samp[swz(t | (k << 9))];
  greg<1, 1>(a, gsh + 6 * 8, 0);
  greg<2, 2>(a, gsh + 5 * 8, 0);
  greg<4, 4>(a, gsh + 4 * 8, 0);
#pragma unroll
  for (int k = 0; k < 8; k++)
    ws[base + t + (k << 9)] = packa(a[k]);
}

// ====== Pass 2: R0 g12..15 + conj b in {0..7,13,14,15}.  Window {g0..g7,g12..g15};
// local l0-7 = g0-7, l8-11 = g12-15; fixed wb = g8..11.
// Ordering: all R0 (rounds A,B) precede every conj gate except conj14, whose
// mask{g13,g14}/sel{g14,g15} exclude g12 (commutes with pending R0 g12). ======

__global__ void __launch_bounds__(NT, 4) pass2_k(const float* __restrict__ th,
                                                 __half2* __restrict__ ws) {
  __shared__ float gsh[256];
  __shared__ float2 samp[4096];
  int t = threadIdx.x, blk = blockIdx.x;
  int batch = (blk & 7) + ((blk >> 7) << 3), wb = (blk >> 3) & 15;
  int bbase = batch << 16;
  float2 a[8];
  // Round A: tile {l9,l10,l11} = {g13,g14,g15}: l = t | (k<<9)
#pragma unroll
  for (int k = 0; k < 8; k++) {
    int g = (t & 255) | (wb << 8) | (((t >> 8) & 1) << 12) | (k << 13);
    a[k] = unpacka(ws[bbase + g]);
  }
  compute_gates(th, gsh);
  __syncthreads();   // gsh ready
  greg<1, 1>(a, gsh + 2 * 8, 0);         // R0 g13 (qubit 2)
  greg<2, 2>(a, gsh + 1 * 8, 0);         // R0 g14
  greg<4, 4>(a, gsh + 0 * 8, 0);         // R0 g15
  greg<3, 6>(a, gsh + (16 + 1) * 8, 0);  // conj14: mask{g13,g14}, sel{g14,g15} in-tile
#pragma unroll
  for (int k = 0; k < 8; k++) samp[swz(t | (k << 9))] = a[k];
  __syncthreads();
  // Round B: tile {l0,l8,l9} = {g0,g12,g13}:
  // l = (k&1) | ((t&127)<<1) | (((k>>1)&3)<<8) | ((t>>7)<<10)
#pragma unroll
  for (int k = 0; k < 8; k++)
    a[k] = samp[swz((k & 1) | ((t & 127) << 1) | (((k >> 1) & 3) << 8) | ((t >> 7) << 10))];
  {
    int cB = __popc(t >> 7) & 1;           // conj13 out-of-tile sel {g14,g15} = t bits 7,8
    greg<2, 2>(a, gsh + 3 * 8, 0);         // R0 g12 (qubit 3) = k bit 1
    greg<6, 4>(a, gsh + (16 + 2) * 8, cB); // conj13: mask{g12,g13}=k1,k2; sel in-tile {g13}
  }
#pragma unroll
  for (int k = 0; k < 8; k++)
    samp[swz((k & 1) | ((t & 127) << 1) | (((k >> 1) & 3) << 8) | ((t >> 7) << 10))] = a[k];
  __syncthreads();
  // Round C: tile {l0,l10,l11} = {g0,g14,g15}: l = (k&1) | (t<<1) | ((k>>1)<<10)
#pragma unroll
  for (int k = 0; k < 8; k++)
    a[k] = samp[swz((k & 1) | (t << 1) | ((k >> 1) << 10))];
  {
    int cC = (__popc(t) + __popc(wb)) & 1;   // out sel: g1-7,g12,g13 (=t) + g8-11 (wb)
    greg<6, 3>(a, gsh + (16 + 0) * 8, cC);   // conj15: mask{g14,g15}, sel 0x7FFF
    greg<7, 7>(a, gsh + (16 + 15) * 8, cC);  // conj0:  mask{g0,g14,g15}, sel 0xFFFF
  }
#pragma unroll
  for (int k = 0; k < 8; k++)
    samp[swz((k & 1) | (t << 1) | ((k >> 1) << 10))] = a[k];
  __syncthreads();
  // Round D: tile {l0,l1,l2}: l = k | (t<<3)
#pragma unroll
  for (int k = 0; k < 8; k++) a[k] = samp[swz(k | (t << 3))];
  {
    int cD = (__popc(t) + __popc(wb)) & 1;   // out: g3-7,g12-15 (=t) + wb
    greg<3, 6>(a, gsh + (16 + 14) * 8, cD);  // conj1: mask{g0,g1}, sel 0xFFFE
    greg<6, 4>(a, gsh + (16 + 13) * 8, cD);  // conj2: mask{g1,g2}, sel 0xFFFC
  }
#pragma unroll
  for (int k = 0; k < 8; k++) samp[swz(k | (t << 3))] = a[k];
  __syncthreads();
  // Round E: tile {l2,l3,l4}: l = (t&3) | (k<<2) | ((t>>2)<<5)
#pragma unroll
  for (int k = 0; k < 8; k++)
    a[k] = samp[swz((t & 3) | (k << 2) | ((t >> 2) << 5))];
  {
    int cE = (__popc(t >> 2) + __popc(wb)) & 1;  // out: g5-7,g12-15 + wb
    greg<3, 6>(a, gsh + (16 + 12) * 8, cE);  // conj3: mask{g2,g3}, sel 0xFFF8
    greg<6, 4>(a, gsh + (16 + 11) * 8, cE);  // conj4: mask{g3,g4}, sel 0xFFF0
  }
#pragma unroll
  for (int k = 0; k < 8; k++)
    samp[swz((t & 3) | (k << 2) | ((t >> 2) << 5))] = a[k];
  __syncthreads();
  // Round F: tile {l4,l5,l6}: l = (t&15) | (k<<4) | ((t>>4)<<7)
#pragma unroll
  for (int k = 0; k < 8; k++)
    a[k] = samp[swz((t & 15) | (k << 4) | ((t >> 4) << 7))];
  {
    int cF = (__popc(t >> 4) + __popc(wb)) & 1;  // out: g7,g12-15 + wb
    greg<3, 6>(a, gsh + (16 + 10) * 8, cF);  // conj5: mask{g4,g5}, sel 0xFFE0
    greg<6, 4>(a, gsh + (16 + 9) * 8, cF);   // conj6: mask{g5,g6}, sel 0xFFC0
  }
#pragma unroll
  for (int k = 0; k < 8; k++)
    samp[swz((t & 15) | (k << 4) | ((t >> 4) << 7))] = a[k];
  __syncthreads();
  // Round G: tile {l6,l7,l8} = {g6,g7,g12}: l = (t&63) | (k<<6) | ((t>>6)<<9); store
#pragma unroll
  for (int k = 0; k < 8; k++)
    a[k] = samp[swz((t & 63) | (k << 6) | ((t >> 6) << 9))];
  {
    int cG = (__popc(t >> 6) + __popc(wb)) & 1;  // out: g13,g14,g15 (t>>6) + wb
    greg<3, 6>(a, gsh + (16 + 8) * 8, cG);   // conj7: mask{g6,g7}, sel 0xFF80 (g12 in SK)
  }
#pragma unroll
  for (int k = 0; k < 8; k++) {
    int l = (t & 63) | (k << 6) | ((t >> 6) << 9);
    int g = (l & 255) | (wb << 8) | ((l >> 8) << 12);
    ws[bbase + g] = packa(a[k]);
  }
}

// ====== Pass 3: gather B[f(j)], standard R1 gates on j-bits 8..12, out[f^{-1}(j)] ======
// Local l0-6 = j0-6, l7 = j8, l8-11 = j9-12; fixed {j7,j13,j14,j15} = wb.
// All gates on distinct bits - commute freely.

__global__ void __launch_bounds__(NT, 4) pass3_k(const float* __restrict__ th,
                                                 const __half2* __restrict__ ws,
                                                 float* __restrict__ out) {
  __shared__ float gsh[256];
  __shared__ float2 samp[4096];
  int t = threadIdx.x, blk = blockIdx.x;
  int batch = (blk & 7) + ((blk >> 7) << 3), wb = (blk >> 3) & 15;
  int bbase = batch << 16;
  int fix = ((wb & 1) << 7) | ((wb >> 1) << 13);
  float2 a[8];
  // Round A: tile {l7,l8,l9} = {j8,j9,j10}: l = (t&127) | (k<<7) | ((t>>7)<<10)
#pragma unroll
  for (int k = 0; k < 8; k++) {
    int l = (t & 127) | (k << 7) | ((t >> 7) << 10);
    int j = (l & 127) | (((l >> 7) & 1) << 8) | ((l >> 8) << 9) | fix;
    a[k] = unpacka(ws[bbase + fperm(j)]);
  }
  compute_gates(th, gsh);
  __syncthreads();   // gsh ready
  greg<1, 1>(a, gsh + (16 + 7) * 8, 0);   // j8  (qubit 7)
  greg<2, 2>(a, gsh + (16 + 6) * 8, 0);   // j9
  greg<4, 4>(a, gsh + (16 + 5) * 8, 0);   // j10
#pragma unroll
  for (int k = 0; k < 8; k++)
    samp[swz((t & 127) | (k << 7) | ((t >> 7) << 10))] = a[k];
  __syncthreads();
  // Round B: tile {l0,l10,l11} = {j0,j11,j12}: l = (k&1) | (t<<1) | ((k>>1)<<10)
#pragma unroll
  for (int k = 0; k < 8; k++)
    a[k] = samp[swz((k & 1) | (t << 1) | ((k >> 1) << 10))];
  greg<2, 2>(a, gsh + (16 + 4) * 8, 0);   // j11
  greg<4, 4>(a, gsh + (16 + 3) * 8, 0);   // j12
#pragma unroll
  for (int k = 0; k < 8; k++) {
    int l = (k & 1) | (t << 1) | ((k >> 1) << 10);
    int j = (l & 127) | (((l >> 7) & 1) << 8) | ((l >> 8) << 9) | fix;
    float pr = a[k].x * a[k].x + a[k].y * a[k].y;
    __builtin_nontemporal_store(pr, &out[bbase + finv16(j)]);
  }
}

// ====================== Launcher ======================

extern "C" void kernel_launch(void* const* d_in, const int* in_sizes, int n_in,
                              void* d_out, int out_size, void* d_ws, size_t ws_size,
                              hipStream_t stream) {
  const float* th  = (const float*)d_in[0];   // (2,3,16)
  const float* xre = (const float*)d_in[1];   // (32,65536)
  const float* xim = (const float*)d_in[2];   // (32,65536)
  float* out = (float*)d_out;                 // (32,65536) fp32

  __half2* amp = (__half2*)d_ws;              // 2M half2 = 8 MB state

  pass1_k<<<512, NT, 0, stream>>>(th, xre, xim, amp);
  pass2_k<<<512, NT, 0, stream>>>(th, amp);
  pass3_k<<<512, NT, 0, stream>>>(th, amp, out);
}